// Round 1
// baseline (458.406 us; speedup 1.0000x reference)
//
#include <hip/hip_runtime.h>
#include <hip/hip_fp16.h>

// SparseGraphWaveletLayer: out = relu( (phi·diag(theta)) @ (phi_inv @ (F_sparse @ W)) )
// N=50000, IN_CH=256, OUT_CH=128, NNZ=800000 per sparse matrix.
//
// Round 13 -> 14: replace the two-pass bucket sort (phases C+D with an 8B/edge
// `eb` intermediate and two LDS-atomic sort passes) with a direct counting
// sort to CSR:
//   zero -> per-row global hist -> chunk scan -> chunk-base + cursor init ->
//   one-pass scatter to final compressed CSR slots via per-row atomic cursors.
// Deletes the eb buffer (-38.4 MB HBM round-trip), deletes phase D, keeps
// launch count at 8. Edge stays compressed: col(u16) | fp16(val)<<16.
// Within-row edge order is now nondeterministic (atomic cursors) -> only FP
// summation order changes (absmax slack: 0.125 used of ~0.76 budget).

#define OUT_CH 128
#define HALF_CH 64
#define RPB 256           // rows per chunk (scan granularity)
#define RPB_SHIFT 8
#define MAX_NB 256        // supports N <= 65536
#define EPB 4096          // edges per block in hist/scatter (256 thr x 16)
#define EPT 16            // edges per thread

// ---------------- zero the per-row counter table ----------------------------

__global__ __launch_bounds__(256) void zero4_kernel(int4* __restrict__ p, int n4)
{
    int i = blockIdx.x * 256 + threadIdx.x;
    if (i < n4) p[i] = make_int4(0, 0, 0, 0);
}

// ---------------- per-row global histogram ----------------------------------

__global__ __launch_bounds__(256) void row_hist_kernel(
    const int* __restrict__ rows0, int n0,
    const int* __restrict__ rows1, int n1,
    const int* __restrict__ rows2, int n2,
    int* __restrict__ cnt, int S)
{
    int m = blockIdx.y;
    const int* rows = (m == 0) ? rows0 : (m == 1) ? rows1 : rows2;
    int nnz         = (m == 0) ? n0    : (m == 1) ? n1    : n2;
    int* c = cnt + (size_t)m * S;
    int base = blockIdx.x * EPB;
    #pragma unroll
    for (int k = 0; k < EPT; ++k) {
        int i = base + k * 256 + threadIdx.x;
        if (i < nnz) atomicAdd(&c[rows[i]], 1);
    }
}

// ---------------- per-chunk (256-row) exclusive scan ------------------------
// off[r] <- exclusive prefix of counts within the chunk; totals[chunk] <- sum.
// Padded rows (r >= n) read zeroed counters, so no bounds checks in the scan.

__global__ __launch_bounds__(256) void scan_chunks_kernel(
    const int* __restrict__ cnt, int* __restrict__ off,
    int* __restrict__ totals, int S, int n, int NB)
{
    int m = blockIdx.y, b = blockIdx.x, t = threadIdx.x;
    int r = b * RPB + t;
    int x = cnt[(size_t)m * S + r];
    int lane = t & 63, wid = t >> 6;
    int incl = x;
    #pragma unroll
    for (int s = 1; s < 64; s <<= 1) {
        int y = __shfl_up(incl, s);
        if (lane >= s) incl += y;
    }
    __shared__ int wtot[4], wbase[4];
    if (lane == 63) wtot[wid] = incl;
    __syncthreads();
    if (t == 0) {
        int run = 0;
        #pragma unroll
        for (int w = 0; w < 4; ++w) { int v = wtot[w]; wbase[w] = run; run += v; }
        totals[m * NB + b] = run;
    }
    __syncthreads();
    int excl = wbase[wid] + incl - x;
    if (r < n) off[(size_t)m * (n + 1) + r] = excl;
}

// ---------------- add chunk bases, init per-row cursors ---------------------
// Each block redundantly reduces totals[0..b) (NB <= 256, one load per lane).

__global__ __launch_bounds__(256) void offcur_kernel(
    const int* __restrict__ totals, int* __restrict__ off,
    int* __restrict__ cnt, int S, int n, int NB,
    int n0, int n1, int n2)
{
    int m = blockIdx.y, b = blockIdx.x, t = threadIdx.x;
    int x = (t < b) ? totals[m * NB + t] : 0;   // b < NB <= 256
    int lane = t & 63, wid = t >> 6;
    int v = x;
    #pragma unroll
    for (int s = 1; s < 64; s <<= 1) v += __shfl_xor(v, s);
    __shared__ int ws[4];
    __shared__ int base_s;
    if (lane == 0) ws[wid] = v;
    __syncthreads();
    if (t == 0) base_s = ws[0] + ws[1] + ws[2] + ws[3];
    __syncthreads();
    int base = base_s;
    int r = b * RPB + t;
    if (r < n) {
        int val = off[(size_t)m * (n + 1) + r] + base;
        off[(size_t)m * (n + 1) + r] = val;
        cnt[(size_t)m * S + r] = val;            // becomes the scatter cursor
    }
    if (b == NB - 1 && t == 0) {
        int nnz = (m == 0) ? n0 : (m == 1) ? n1 : n2;
        off[(size_t)m * (n + 1) + n] = nnz;
    }
}

// ---------------- one-pass direct scatter to compressed CSR -----------------

__global__ __launch_bounds__(256) void scatter_csr_kernel(
    const int* __restrict__ rows0, const int* __restrict__ cols0, const float* __restrict__ vals0, int n0,
    const int* __restrict__ rows1, const int* __restrict__ cols1, const float* __restrict__ vals1, int n1,
    const int* __restrict__ rows2, const int* __restrict__ cols2, const float* __restrict__ vals2, int n2,
    const float* __restrict__ theta,
    int* __restrict__ cur, int S,
    unsigned int* __restrict__ ec0, unsigned int* __restrict__ ec1, unsigned int* __restrict__ ec2)
{
    int m = blockIdx.y;
    const int* rows; const int* cols; const float* vals; int nnz; unsigned int* ec;
    if (m == 0)      { rows = rows0; cols = cols0; vals = vals0; nnz = n0; ec = ec0; }
    else if (m == 1) { rows = rows1; cols = cols1; vals = vals1; nnz = n1; ec = ec1; }
    else             { rows = rows2; cols = cols2; vals = vals2; nnz = n2; ec = ec2; }
    int* c = cur + (size_t)m * S;
    bool fold = (m == 2);
    int base = blockIdx.x * EPB;
    #pragma unroll
    for (int k = 0; k < EPT; ++k) {
        int i = base + k * 256 + threadIdx.x;
        if (i < nnz) {
            int r = rows[i], col = cols[i];
            float v = vals[i];
            if (fold) v *= theta[col];
            int pos = atomicAdd(&c[r], 1);
            unsigned short h = __half_as_ushort(__float2half_rn(v));
            ec[pos] = (unsigned int)(col & 0xFFFF) | ((unsigned int)h << 16);
        }
    }
}

// ---------------- gather-side CSR SpMM, 4B compressed edges, unroll-8 -------

template<bool SRC_H, bool DST_H, bool RELU>
__global__ __launch_bounds__(256) void spmm_csr_kernel(
    const int* __restrict__ off, const unsigned int* __restrict__ edges,
    const void* __restrict__ dense_v, void* __restrict__ out_v, int nrows)
{
    int lane = threadIdx.x & 63;
    int r = blockIdx.x * 4 + (threadIdx.x >> 6);
    if (r >= nrows) return;
    int j   = __builtin_amdgcn_readfirstlane(off[r]);
    int end = __builtin_amdgcn_readfirstlane(off[r + 1]);
    const float2*  df = (const float2*)dense_v;
    const __half2* dh = (const __half2*)dense_v;

    float2 a0 = make_float2(0.f, 0.f), a1 = make_float2(0.f, 0.f);

    for (; j + 8 <= end; j += 8) {
        unsigned int e[8]; float2 d[8];
        #pragma unroll
        for (int k = 0; k < 8; ++k) e[k] = edges[j + k];
        #pragma unroll
        for (int k = 0; k < 8; ++k) {
            if (SRC_H) d[k] = __half22float2(dh[(size_t)(e[k] & 0xFFFF) * HALF_CH + lane]);
            else       d[k] = df[(size_t)(e[k] & 0xFFFF) * HALF_CH + lane];
        }
        #pragma unroll
        for (int k = 0; k < 8; ++k) {
            float v = __half2float(__ushort_as_half((unsigned short)(e[k] >> 16)));
            if (k & 1) { a1.x = fmaf(v, d[k].x, a1.x); a1.y = fmaf(v, d[k].y, a1.y); }
            else       { a0.x = fmaf(v, d[k].x, a0.x); a0.y = fmaf(v, d[k].y, a0.y); }
        }
    }
    for (; j + 4 <= end; j += 4) {
        unsigned int e[4]; float2 d[4];
        #pragma unroll
        for (int k = 0; k < 4; ++k) e[k] = edges[j + k];
        #pragma unroll
        for (int k = 0; k < 4; ++k) {
            if (SRC_H) d[k] = __half22float2(dh[(size_t)(e[k] & 0xFFFF) * HALF_CH + lane]);
            else       d[k] = df[(size_t)(e[k] & 0xFFFF) * HALF_CH + lane];
        }
        #pragma unroll
        for (int k = 0; k < 4; ++k) {
            float v = __half2float(__ushort_as_half((unsigned short)(e[k] >> 16)));
            if (k & 1) { a1.x = fmaf(v, d[k].x, a1.x); a1.y = fmaf(v, d[k].y, a1.y); }
            else       { a0.x = fmaf(v, d[k].x, a0.x); a0.y = fmaf(v, d[k].y, a0.y); }
        }
    }
    for (; j < end; ++j) {
        unsigned int e0 = edges[j];
        float2 d0;
        if (SRC_H) d0 = __half22float2(dh[(size_t)(e0 & 0xFFFF) * HALF_CH + lane]);
        else       d0 = df[(size_t)(e0 & 0xFFFF) * HALF_CH + lane];
        float v0 = __half2float(__ushort_as_half((unsigned short)(e0 >> 16)));
        a0.x = fmaf(v0, d0.x, a0.x); a0.y = fmaf(v0, d0.y, a0.y);
    }
    float2 res = make_float2(a0.x + a1.x, a0.y + a1.y);
    if (RELU) { res.x = fmaxf(res.x, 0.f); res.y = fmaxf(res.y, 0.f); }
    if (DST_H) ((__half2*)out_v)[(size_t)r * HALF_CH + lane] = __float22half2_rn(res);
    else       ((float2*) out_v)[(size_t)r * HALF_CH + lane] = res;
}

// ---------------- fallback (round-0) atomic path ----------------

__global__ __launch_bounds__(256) void spmm_atomic_kernel(
    const int* __restrict__ rows, const int* __restrict__ cols,
    const float* __restrict__ vals, const float* __restrict__ theta,
    const float* __restrict__ dense, float* __restrict__ out, int nnz)
{
    int idx = blockIdx.x * blockDim.x + threadIdx.x;
    int e = idx >> 7;
    int f = idx & (OUT_CH - 1);
    if (e >= nnz) return;
    int r = rows[e];
    int c = cols[e];
    float v = vals[e];
    if (theta != nullptr) v *= theta[c];
    atomicAdd(&out[(size_t)r * OUT_CH + f], v * dense[(size_t)c * OUT_CH + f]);
}

__global__ __launch_bounds__(256) void relu_kernel(float* __restrict__ out, int n4)
{
    int i = blockIdx.x * blockDim.x + threadIdx.x;
    if (i >= n4) return;
    float4 v = ((float4*)out)[i];
    v.x = fmaxf(v.x, 0.f); v.y = fmaxf(v.y, 0.f);
    v.z = fmaxf(v.z, 0.f); v.w = fmaxf(v.w, 0.f);
    ((float4*)out)[i] = v;
}

// ---------------- launch ----------------

static inline size_t align16(size_t x) { return (x + 15) & ~(size_t)15; }

extern "C" void kernel_launch(void* const* d_in, const int* in_sizes, int n_in,
                              void* d_out, int out_size, void* d_ws, size_t ws_size,
                              hipStream_t stream)
{
    const int*   phi_idx   = (const int*)d_in[0];
    const float* phi_vals  = (const float*)d_in[1];
    const int*   phii_idx  = (const int*)d_in[2];
    const float* phii_vals = (const float*)d_in[3];
    const int*   feat_idx  = (const int*)d_in[4];
    const float* feat_vals = (const float*)d_in[5];
    const float* W         = (const float*)d_in[6];
    const float* theta     = (const float*)d_in[7];

    const int nnz_phi  = in_sizes[1];
    const int nnz_phii = in_sizes[3];
    const int nnz_feat = in_sizes[5];
    const int n_nodes  = in_sizes[7];
    const int in_ch    = in_sizes[6] / OUT_CH;
    const size_t dense_elems = (size_t)n_nodes * OUT_CH;
    const long long total_e = (long long)nnz_feat + nnz_phii + nnz_phi;

    const int NB = (n_nodes + RPB - 1) >> RPB_SHIFT;   // row chunks
    const int S  = NB * RPB;                           // padded rows per matrix
    int max_nnz = nnz_feat > nnz_phii ? nnz_feat : nnz_phii;
    if (nnz_phi > max_nnz) max_nnz = nnz_phi;
    const int NBLK = (max_nnz + EPB - 1) / EPB;

    // ---- workspace layout ----
    size_t p = 0;
    size_t filtered_off = p; p += align16(dense_elems * sizeof(__half));
    size_t tmp_off      = p; p += align16(dense_elems * sizeof(__half));
    size_t off_off      = p; p += align16((size_t)3 * (n_nodes + 1) * sizeof(int));
    size_t cnt_off      = p; p += align16((size_t)3 * S * sizeof(int));
    size_t tot_off      = p; p += align16((size_t)3 * NB * sizeof(int));
    size_t ec_off       = p; p += align16((size_t)total_e * sizeof(unsigned int));
    size_t need = p;

    char* ws = (char*)d_ws;
    dim3 block(256);

    bool fast_ok = (ws_size >= need) && (NB <= MAX_NB) && (n_nodes <= 65536) &&
                   (in_ch <= 65536);

    if (fast_ok) {
        __half* filtered = (__half*)(ws + filtered_off);
        __half* tmp      = (__half*)(ws + tmp_off);
        int* off_arr    = (int*)(ws + off_off);
        int* cnt        = (int*)(ws + cnt_off);
        int* totals     = (int*)(ws + tot_off);
        unsigned int* ec0 = (unsigned int*)(ws + ec_off);
        unsigned int* ec1 = ec0 + nnz_feat;
        unsigned int* ec2 = ec1 + nnz_phii;

        const int* rows0 = feat_idx;  const int* cols0 = feat_idx + nnz_feat;
        const int* rows1 = phii_idx;  const int* cols1 = phii_idx + nnz_phii;
        const int* rows2 = phi_idx;   const int* cols2 = phi_idx  + nnz_phi;

        {   // zero the per-row counters (3*S ints, S multiple of 256)
            int n4 = (3 * S) / 4;
            zero4_kernel<<<dim3((n4 + 255) / 256), block, 0, stream>>>(
                (int4*)cnt, n4);
        }

        row_hist_kernel<<<dim3(NBLK, 3), block, 0, stream>>>(
            rows0, nnz_feat, rows1, nnz_phii, rows2, nnz_phi, cnt, S);

        scan_chunks_kernel<<<dim3(NB, 3), block, 0, stream>>>(
            cnt, off_arr, totals, S, n_nodes, NB);

        offcur_kernel<<<dim3(NB, 3), block, 0, stream>>>(
            totals, off_arr, cnt, S, n_nodes, NB,
            nnz_feat, nnz_phii, nnz_phi);

        scatter_csr_kernel<<<dim3(NBLK, 3), block, 0, stream>>>(
            rows0, cols0, feat_vals, nnz_feat,
            rows1, cols1, phii_vals, nnz_phii,
            rows2, cols2, phi_vals,  nnz_phi,
            theta, cnt, S, ec0, ec1, ec2);

        int* off_f  = off_arr;
        int* off_pi = off_arr + (n_nodes + 1);
        int* off_p  = off_arr + 2 * (n_nodes + 1);

        dim3 grid_r((unsigned)((n_nodes + 3) / 4));
        // stage 1: src fp32 W, dst fp16 filtered
        spmm_csr_kernel<false, true, false><<<grid_r, block, 0, stream>>>(
            off_f,  ec0, (const void*)W, (void*)filtered, n_nodes);
        // stage 2: src fp16 filtered, dst fp16 tmp
        spmm_csr_kernel<true, true, false><<<grid_r, block, 0, stream>>>(
            off_pi, ec1, (const void*)filtered, (void*)tmp, n_nodes);
        // stage 3: src fp16 tmp, dst fp32 out + relu
        spmm_csr_kernel<true, false, true><<<grid_r, block, 0, stream>>>(
            off_p,  ec2, (const void*)tmp, d_out, n_nodes);
    } else {
        // fallback: round-0 atomic path (needs only 2 fp32 dense buffers)
        float* filtered = (float*)ws;
        float* tmp      = filtered + dense_elems;
        hipMemsetAsync(filtered, 0, 2 * dense_elems * sizeof(float), stream);
        hipMemsetAsync(d_out, 0, (size_t)out_size * sizeof(float), stream);
        {
            long long t = (long long)nnz_feat * OUT_CH;
            spmm_atomic_kernel<<<dim3((unsigned)((t + 255) / 256)), block, 0, stream>>>(
                feat_idx, feat_idx + nnz_feat, feat_vals, nullptr, W, filtered, nnz_feat);
        }
        {
            long long t = (long long)nnz_phii * OUT_CH;
            spmm_atomic_kernel<<<dim3((unsigned)((t + 255) / 256)), block, 0, stream>>>(
                phii_idx, phii_idx + nnz_phii, phii_vals, nullptr, filtered, tmp, nnz_phii);
        }
        {
            long long t = (long long)nnz_phi * OUT_CH;
            spmm_atomic_kernel<<<dim3((unsigned)((t + 255) / 256)), block, 0, stream>>>(
                phi_idx, phi_idx + nnz_phi, phi_vals, theta, tmp, (float*)d_out, nnz_phi);
        }
        {
            int n4 = out_size / 4;
            relu_kernel<<<dim3((n4 + 255) / 256), block, 0, stream>>>((float*)d_out, n4);
        }
    }
}